// Round 1
// baseline (123.738 us; speedup 1.0000x reference)
//
#include <hip/hip_runtime.h>
#include <hip/hip_cooperative_groups.h>

namespace cg = cooperative_groups;

// Sinkhorn top-K collapsed to a per-row 1-D Newton solve. B=512, N=4096, K=256, eps=0.1.
// t[n] = exp((1-2*s[n]) * alpha), alpha = 1/(M*eps), M = global max of (s-anchor)^2.
// Solve h(rho) = sum_n rho*t/(rho*t+1) = K (concave, monotone; Newton from below,
// rho0 = K/sum(t)). P1 = mu*w, P0 = mu*(1-w), w = 1/(rho*t+1). Fixed point == the
// reference's machine-converged 200 Sinkhorn sweeps (absmax 9.5e-7, R1-R4).
//
// R6: fuse K1 (global max) + K2 (solve) into ONE cooperative kernel.
//   - 512 blocks x 512 thr = 2 blocks/CU, exactly co-resident (launch_bounds(512,4)
//     caps VGPR at 128 to guarantee it). Row loaded into registers ONCE and kept
//     across grid.sync() -> scores read 8.4 MB instead of 16.8 MB, and one
//     inter-dispatch gap removed.
//   - blkmax publish/gather uses agent-scope atomics (coherent point), avoiding the
//     cross-XCD L2 non-coherence hazard for plain stores around a grid barrier.
//   - Falls back to the proven R5 two-kernel path if cooperative launch errors.
// Harness floor ~69 us (256 MiB ws poison fill ~43 us + out poison + restore + gaps);
// kernel-side floor ~4 us (8.4 MB read + 16.8 MB write @ 6.3 TB/s).

#define NROWS 512
#define NCOLS 4096
#define KSEL 256
#define EPSREG 0.1f
#define NEWTON_ITERS 6

__device__ __forceinline__ float fastrcp(float x) {
#if __has_builtin(__builtin_amdgcn_rcpf)
    return __builtin_amdgcn_rcpf(x);
#else
    return 1.0f / x;
#endif
}

// =====================================================================
// R6 fused cooperative kernel: 512 blocks x 512 thr
// =====================================================================
__global__ __launch_bounds__(512, 4) void fused_kernel(const float* __restrict__ s,
                                                       float* __restrict__ blkmax,
                                                       float* __restrict__ out) {
    const int b   = blockIdx.x;
    const int tid = threadIdx.x;
    const int wv  = tid >> 6;          // wave 0..7
    const int ln  = tid & 63;

    __shared__ __align__(16) float ldsm[8];
    __shared__ __align__(16) float ldss[8];
    __shared__ __align__(16) float lds[2][16];   // Newton ping-pong: 8 x {A,Q}

    // ---- row load, ONCE; lives in registers across the grid barrier
    const float4* srow = (const float4*)(s + (size_t)b * NCOLS);
    const float4 v0 = srow[tid];
    const float4 v1 = srow[tid + 512];
    const float xs[8] = {v0.x, v0.y, v0.z, v0.w, v1.x, v1.y, v1.z, v1.w};

    // ---- phase 1: row max of max(x^2, (x-1)^2)
    float m = 0.f;
#pragma unroll
    for (int e = 0; e < 8; ++e) {
        float x = xs[e];
        m = fmaxf(m, fmaxf(x * x, (x - 1.f) * (x - 1.f)));
    }
#pragma unroll
    for (int off = 32; off >= 1; off >>= 1)
        m = fmaxf(m, __shfl_xor(m, off, 64));
    if (ln == 0) ldsm[wv] = m;
    __syncthreads();
    if (tid == 0) {
        const float4* p = (const float4*)ldsm;
        float4 a0 = p[0], a1 = p[1];
        float rm = fmaxf(fmaxf(fmaxf(a0.x, a0.y), fmaxf(a0.z, a0.w)),
                         fmaxf(fmaxf(a1.x, a1.y), fmaxf(a1.z, a1.w)));
        // agent-scope atomic store: lands at the coherent point, visible to all XCDs
        __hip_atomic_store(&blkmax[b], rm, __ATOMIC_RELAXED, __HIP_MEMORY_SCOPE_AGENT);
    }

    cg::this_grid().sync();            // all 512 row-maxes published

    // ---- phase 2: global max (1 value/thread, coherent loads, coalesced)
    m = __hip_atomic_load(&blkmax[tid], __ATOMIC_RELAXED, __HIP_MEMORY_SCOPE_AGENT);
#pragma unroll
    for (int off = 32; off >= 1; off >>= 1)
        m = fmaxf(m, __shfl_xor(m, off, 64));
    if (ln == 0) ldsm[wv] = m;
    __syncthreads();
    {
        const float4* p = (const float4*)ldsm;   // same-addr broadcast reads: free
        float4 a0 = p[0], a1 = p[1];
        m = fmaxf(fmaxf(fmaxf(a0.x, a0.y), fmaxf(a0.z, a0.w)),
                  fmaxf(fmaxf(a1.x, a1.y), fmaxf(a1.z, a1.w)));
    }
    const float alpha = 1.0f / (m * EPSREG);
    const float c2    = -2.0f * alpha;

    // ---- t = exp((1-2x)*alpha), 8 per thread, + sum(t)
    float t[8];
    float sumt = 0.f;
#pragma unroll
    for (int e = 0; e < 8; ++e) {
        float tt = __expf(fmaf(xs[e], c2, alpha));
        t[e] = tt;
        sumt += tt;
    }
#pragma unroll
    for (int off = 32; off >= 1; off >>= 1)
        sumt += __shfl_xor(sumt, off, 64);
    if (ln == 0) ldss[wv] = sumt;
    __syncthreads();
    {
        const float4* p = (const float4*)ldss;
        float4 a0 = p[0], a1 = p[1];
        sumt = (a0.x + a0.y + a0.z + a0.w) + (a1.x + a1.y + a1.z + a1.w);
    }

    // rho0 = K/sum(t): h(rho0) < K strictly -> monotone Newton from below
    float rho = (float)KSEL / sumt;

#pragma unroll 1
    for (int it = 0; it < NEWTON_ITERS; ++it) {
        float a = 0.f, q = 0.f;
#pragma unroll
        for (int e = 0; e < 8; ++e) {
            float w = fastrcp(fmaf(rho, t[e], 1.0f));
            a += w;
            q = fmaf(w, w, q);
        }
#pragma unroll
        for (int off = 32; off >= 1; off >>= 1) {
            a += __shfl_xor(a, off, 64);
            q += __shfl_xor(q, off, 64);
        }
        const int ph = it & 1;
        if (ln == 0) { lds[ph][wv * 2] = a; lds[ph][wv * 2 + 1] = q; }
        __syncthreads();               // one barrier/iter; ping-pong handles WAR
        a = 0.f; q = 0.f;
        const float4* p = (const float4*)lds[ph];
#pragma unroll
        for (int r = 0; r < 4; ++r) {  // layout a,q,a,q,... -> x,z are A; y,w are Q
            float4 f = p[r];
            a += f.x + f.z;
            q += f.y + f.w;
        }
        // h(rho) = N - A, h'(rho) = (A - Q)/rho
        rho += ((float)(KSEL - NCOLS) + a) * rho / (a - q);
    }

    // ---- write P: out[b,0,n] = mu*(1-w), out[b,1,n] = mu*w
    const float MU = 1.0f / (float)NCOLS;
    float4* o0 = (float4*)(out + (size_t)b * 2 * NCOLS);
    float4* o1 = (float4*)(out + (size_t)b * 2 * NCOLS + NCOLS);
#pragma unroll
    for (int j = 0; j < 2; ++j) {
        float r0[4], r1[4];
#pragma unroll
        for (int e = 0; e < 4; ++e) {
            float w  = fastrcp(fmaf(rho, t[4 * j + e], 1.0f));
            float p1 = MU * w;
            r1[e] = p1;
            r0[e] = MU - p1;
        }
        o0[tid + 512 * j] = make_float4(r0[0], r0[1], r0[2], r0[3]);
        o1[tid + 512 * j] = make_float4(r1[0], r1[1], r1[2], r1[3]);
    }
}

// =====================================================================
// R5 fallback path (proven): K1 per-block max + K2 per-row solve
// =====================================================================
__global__ __launch_bounds__(256) void kmax_kernel(const float4* __restrict__ s4,
                                                   float* __restrict__ blkmax) {
    const int tid = blockIdx.x * 256 + threadIdx.x;   // 131072 threads
    float m = 0.f;
#pragma unroll
    for (int j = 0; j < 4; ++j) {                     // 4*131072 = 524288 float4 = 2M floats
        float4 v = s4[tid + 131072 * j];
        m = fmaxf(m, fmaxf(v.x * v.x, (v.x - 1.f) * (v.x - 1.f)));
        m = fmaxf(m, fmaxf(v.y * v.y, (v.y - 1.f) * (v.y - 1.f)));
        m = fmaxf(m, fmaxf(v.z * v.z, (v.z - 1.f) * (v.z - 1.f)));
        m = fmaxf(m, fmaxf(v.w * v.w, (v.w - 1.f) * (v.w - 1.f)));
    }
#pragma unroll
    for (int off = 32; off >= 1; off >>= 1)
        m = fmaxf(m, __shfl_xor(m, off, 64));
    __shared__ float wmax[4];
    if ((threadIdx.x & 63) == 0) wmax[threadIdx.x >> 6] = m;
    __syncthreads();
    if (threadIdx.x == 0)
        blkmax[blockIdx.x] = fmaxf(fmaxf(wmax[0], wmax[1]), fmaxf(wmax[2], wmax[3]));
}

__global__ __launch_bounds__(512) void sinkhorn_kernel(const float* __restrict__ s,
                                                       const float* __restrict__ blkmax,
                                                       float* __restrict__ out) {
    const int b   = blockIdx.x;
    const int tid = threadIdx.x;
    const int wv  = tid >> 6;
    const int ln  = tid & 63;

    __shared__ __align__(16) float ldsm[8];
    __shared__ __align__(16) float ldss[8];
    __shared__ __align__(16) float lds[2][16];

    const float4* srow = (const float4*)(s + (size_t)b * NCOLS);
    const float4 v0 = srow[tid];
    const float4 v1 = srow[tid + 512];

    float m = blkmax[tid];
#pragma unroll
    for (int off = 32; off >= 1; off >>= 1)
        m = fmaxf(m, __shfl_xor(m, off, 64));
    if (ln == 0) ldsm[wv] = m;
    __syncthreads();
    {
        const float4* p = (const float4*)ldsm;
        float4 a0 = p[0], a1 = p[1];
        m = fmaxf(fmaxf(fmaxf(a0.x, a0.y), fmaxf(a0.z, a0.w)),
                  fmaxf(fmaxf(a1.x, a1.y), fmaxf(a1.z, a1.w)));
    }
    const float alpha = 1.0f / (m * EPSREG);
    const float c2    = -2.0f * alpha;

    float t[8];
    const float xs[8] = {v0.x, v0.y, v0.z, v0.w, v1.x, v1.y, v1.z, v1.w};
    float sumt = 0.f;
#pragma unroll
    for (int e = 0; e < 8; ++e) {
        float tt = __expf(fmaf(xs[e], c2, alpha));
        t[e] = tt;
        sumt += tt;
    }
#pragma unroll
    for (int off = 32; off >= 1; off >>= 1)
        sumt += __shfl_xor(sumt, off, 64);
    if (ln == 0) ldss[wv] = sumt;
    __syncthreads();
    {
        const float4* p = (const float4*)ldss;
        float4 a0 = p[0], a1 = p[1];
        sumt = (a0.x + a0.y + a0.z + a0.w) + (a1.x + a1.y + a1.z + a1.w);
    }

    float rho = (float)KSEL / sumt;

#pragma unroll 1
    for (int it = 0; it < NEWTON_ITERS; ++it) {
        float a = 0.f, q = 0.f;
#pragma unroll
        for (int e = 0; e < 8; ++e) {
            float w = fastrcp(fmaf(rho, t[e], 1.0f));
            a += w;
            q = fmaf(w, w, q);
        }
#pragma unroll
        for (int off = 32; off >= 1; off >>= 1) {
            a += __shfl_xor(a, off, 64);
            q += __shfl_xor(q, off, 64);
        }
        const int ph = it & 1;
        if (ln == 0) { lds[ph][wv * 2] = a; lds[ph][wv * 2 + 1] = q; }
        __syncthreads();
        a = 0.f; q = 0.f;
        const float4* p = (const float4*)lds[ph];
#pragma unroll
        for (int r = 0; r < 4; ++r) {
            float4 f = p[r];
            a += f.x + f.z;
            q += f.y + f.w;
        }
        rho += ((float)(KSEL - NCOLS) + a) * rho / (a - q);
    }

    const float MU = 1.0f / (float)NCOLS;
    float4* o0 = (float4*)(out + (size_t)b * 2 * NCOLS);
    float4* o1 = (float4*)(out + (size_t)b * 2 * NCOLS + NCOLS);
#pragma unroll
    for (int j = 0; j < 2; ++j) {
        float r0[4], r1[4];
#pragma unroll
        for (int e = 0; e < 4; ++e) {
            float w  = fastrcp(fmaf(rho, t[4 * j + e], 1.0f));
            float p1 = MU * w;
            r1[e] = p1;
            r0[e] = MU - p1;
        }
        o0[tid + 512 * j] = make_float4(r0[0], r0[1], r0[2], r0[3]);
        o1[tid + 512 * j] = make_float4(r1[0], r1[1], r1[2], r1[3]);
    }
}

extern "C" void kernel_launch(void* const* d_in, const int* in_sizes, int n_in,
                              void* d_out, int out_size, void* d_ws, size_t ws_size,
                              hipStream_t stream) {
    const float* scores = (const float*)d_in[0];
    float* out = (float*)d_out;
    float* blkmax = (float*)d_ws;   // 512 floats; every slot written before read

    void* args[] = {(void*)&scores, (void*)&blkmax, (void*)&out};
    hipError_t err = hipLaunchCooperativeKernel((const void*)fused_kernel,
                                                dim3(NROWS), dim3(512),
                                                args, 0, stream);
    if (err != hipSuccess) {
        // fallback: proven R5 two-kernel path
        hipLaunchKernelGGL(kmax_kernel, dim3(512), dim3(256), 0, stream,
                           (const float4*)scores, blkmax);
        hipLaunchKernelGGL(sinkhorn_kernel, dim3(NROWS), dim3(512), 0, stream,
                           scores, blkmax, out);
    }
}

// Round 2
// 70.531 us; speedup vs baseline: 1.7544x; 1.7544x over previous
//
#include <hip/hip_runtime.h>

// Sinkhorn top-K collapsed to a per-row 1-D Newton solve. B=512, N=4096, K=256, eps=0.1.
// t[n] = exp((1-2*s[n]) * alpha), alpha = 1/(M*eps), M = global max of (s-anchor)^2.
// Solve h(rho) = sum_n rho*t/(rho*t+1) = K (concave, monotone; Newton from below,
// rho0 = K/sum(t)). P1 = mu*w, P0 = mu*(1-w), w = 1/(rho*t+1). Fixed point == the
// reference's machine-converged 200 Sinkhorn sweeps (absmax 9.5e-7, R1-R4).
//
// R7: revert R6's cooperative fusion (grid.sync() measured ~50 us on 512 blocks —
// the software barrier through the coherent point dwarfs any traffic savings;
// fused_kernel was 57 us vs ~7 us for the two-kernel path). Back to R5's two
// dispatches, with one change: K1 is now ROW-PER-BLOCK with the SAME grid size
// (512 blocks) as K2. Same grid => same round-robin block->XCD mapping => K1
// block b warms row b into the XCD L2 that K2 block b reads from. K2's 8.4 MB
// score re-read becomes mostly L2-hit instead of HBM (locality heuristic only;
// correctness independent of the mapping).
// Harness floor ~69 us (256 MiB ws poison fill ~43 us + out poison + restore + gaps);
// kernel-side floor ~4-5 us.

#define NROWS 512
#define NCOLS 4096
#define KSEL 256
#define EPSREG 0.1f
#define NEWTON_ITERS 6

__device__ __forceinline__ float fastrcp(float x) {
#if __has_builtin(__builtin_amdgcn_rcpf)
    return __builtin_amdgcn_rcpf(x);
#else
    return 1.0f / x;
#endif
}

// ---- K1: per-ROW max of max(s^2,(s-1)^2); 512 blocks (one row each) x 256 thr ----
// Row b = 4096 floats = 1024 float4; 256 threads x 4 float4 each, coalesced.
__global__ __launch_bounds__(256) void kmax_kernel(const float4* __restrict__ s4,
                                                   float* __restrict__ blkmax) {
    const int b   = blockIdx.x;
    const int tid = threadIdx.x;
    const float4* row = s4 + (size_t)b * 1024;
    float m = 0.f;
#pragma unroll
    for (int j = 0; j < 4; ++j) {
        float4 v = row[tid + 256 * j];
        m = fmaxf(m, fmaxf(v.x * v.x, (v.x - 1.f) * (v.x - 1.f)));
        m = fmaxf(m, fmaxf(v.y * v.y, (v.y - 1.f) * (v.y - 1.f)));
        m = fmaxf(m, fmaxf(v.z * v.z, (v.z - 1.f) * (v.z - 1.f)));
        m = fmaxf(m, fmaxf(v.w * v.w, (v.w - 1.f) * (v.w - 1.f)));
    }
#pragma unroll
    for (int off = 32; off >= 1; off >>= 1)
        m = fmaxf(m, __shfl_xor(m, off, 64));
    __shared__ float wmax[4];
    if ((tid & 63) == 0) wmax[tid >> 6] = m;
    __syncthreads();
    if (tid == 0)
        blkmax[b] = fmaxf(fmaxf(wmax[0], wmax[1]), fmaxf(wmax[2], wmax[3]));
}

// ---- K2: per-row Newton solve + write P; 512 blocks x 512 thr (8 waves) ----
__global__ __launch_bounds__(512) void sinkhorn_kernel(const float* __restrict__ s,
                                                       const float* __restrict__ blkmax,
                                                       float* __restrict__ out) {
    const int b   = blockIdx.x;
    const int tid = threadIdx.x;
    const int wv  = tid >> 6;          // wave 0..7
    const int ln  = tid & 63;

    __shared__ __align__(16) float ldsm[8];
    __shared__ __align__(16) float ldss[8];
    __shared__ __align__(16) float lds[2][16];   // Newton ping-pong: 8 x {A,Q}

    // ---- row load (2 independent float4/thread), issued first; L2-hot from K1
    const float4* srow = (const float4*)(s + (size_t)b * NCOLS);
    const float4 v0 = srow[tid];
    const float4 v1 = srow[tid + 512];

    // ---- global max from 512 row maxes (1/thread, coalesced, L2/L3-hot)
    float m = blkmax[tid];
#pragma unroll
    for (int off = 32; off >= 1; off >>= 1)
        m = fmaxf(m, __shfl_xor(m, off, 64));
    if (ln == 0) ldsm[wv] = m;
    __syncthreads();                   // barrier 1
    {
        const float4* p = (const float4*)ldsm;   // same-addr broadcast reads: free
        float4 a0 = p[0], a1 = p[1];
        m = fmaxf(fmaxf(fmaxf(a0.x, a0.y), fmaxf(a0.z, a0.w)),
                  fmaxf(fmaxf(a1.x, a1.y), fmaxf(a1.z, a1.w)));
    }
    const float alpha = 1.0f / (m * EPSREG);
    const float c2    = -2.0f * alpha;

    // ---- t = exp((1-2x)*alpha), 8 per thread, + sum(t)
    float t[8];
    const float xs[8] = {v0.x, v0.y, v0.z, v0.w, v1.x, v1.y, v1.z, v1.w};
    float sumt = 0.f;
#pragma unroll
    for (int e = 0; e < 8; ++e) {
        float tt = __expf(fmaf(xs[e], c2, alpha));
        t[e] = tt;
        sumt += tt;
    }
#pragma unroll
    for (int off = 32; off >= 1; off >>= 1)
        sumt += __shfl_xor(sumt, off, 64);
    if (ln == 0) ldss[wv] = sumt;
    __syncthreads();                   // barrier 2
    {
        const float4* p = (const float4*)ldss;
        float4 a0 = p[0], a1 = p[1];
        sumt = (a0.x + a0.y + a0.z + a0.w) + (a1.x + a1.y + a1.z + a1.w);
    }

    // rho0 = K/sum(t): h(rho0) < K strictly -> monotone Newton from below
    float rho = (float)KSEL / sumt;

#pragma unroll 1
    for (int it = 0; it < NEWTON_ITERS; ++it) {
        float a = 0.f, q = 0.f;
#pragma unroll
        for (int e = 0; e < 8; ++e) {
            float w = fastrcp(fmaf(rho, t[e], 1.0f));
            a += w;
            q = fmaf(w, w, q);
        }
#pragma unroll
        for (int off = 32; off >= 1; off >>= 1) {
            a += __shfl_xor(a, off, 64);
            q += __shfl_xor(q, off, 64);
        }
        const int ph = it & 1;
        if (ln == 0) { lds[ph][wv * 2] = a; lds[ph][wv * 2 + 1] = q; }
        __syncthreads();               // one barrier/iter; ping-pong handles WAR
        a = 0.f; q = 0.f;
        const float4* p = (const float4*)lds[ph];
#pragma unroll
        for (int r = 0; r < 4; ++r) {  // layout a,q,a,q,... -> x,z are A; y,w are Q
            float4 f = p[r];
            a += f.x + f.z;
            q += f.y + f.w;
        }
        // h(rho) = N - A, h'(rho) = (A - Q)/rho
        rho += ((float)(KSEL - NCOLS) + a) * rho / (a - q);
    }

    // ---- write P: out[b,0,n] = mu*(1-w), out[b,1,n] = mu*w
    const float MU = 1.0f / (float)NCOLS;
    float4* o0 = (float4*)(out + (size_t)b * 2 * NCOLS);
    float4* o1 = (float4*)(out + (size_t)b * 2 * NCOLS + NCOLS);
#pragma unroll
    for (int j = 0; j < 2; ++j) {
        float r0[4], r1[4];
#pragma unroll
        for (int e = 0; e < 4; ++e) {
            float w  = fastrcp(fmaf(rho, t[4 * j + e], 1.0f));
            float p1 = MU * w;
            r1[e] = p1;
            r0[e] = MU - p1;
        }
        o0[tid + 512 * j] = make_float4(r0[0], r0[1], r0[2], r0[3]);
        o1[tid + 512 * j] = make_float4(r1[0], r1[1], r1[2], r1[3]);
    }
}

extern "C" void kernel_launch(void* const* d_in, const int* in_sizes, int n_in,
                              void* d_out, int out_size, void* d_ws, size_t ws_size,
                              hipStream_t stream) {
    const float* scores = (const float*)d_in[0];
    float* out = (float*)d_out;
    float* blkmax = (float*)d_ws;   // 512 floats; every slot written, no init needed

    hipLaunchKernelGGL(kmax_kernel, dim3(NROWS), dim3(256), 0, stream,
                       (const float4*)scores, blkmax);
    hipLaunchKernelGGL(sinkhorn_kernel, dim3(NROWS), dim3(512), 0, stream,
                       scores, blkmax, out);
}